// Round 1
// baseline (267.598 us; speedup 1.0000x reference)
//
#include <hip/hip_runtime.h>
#include <hip/hip_bf16.h>
#include <math.h>

// Problem constants (GenNeuronStates): B=2,G=4,N=1024,H=16,dq=dv=64
#define B_ 2
#define G_ 4
#define N_ 1024
#define H_ 16
#define D_ 64
#define BG_ (B_*G_)
#define BGH_ (B_*G_*H_)
#define MK 64   // K/V tile rows per flash iteration
#define LOG2E 1.44269504f
#define QSCALE (0.125f * LOG2E)   // folded into Q during transpose

typedef __bf16 bf16;
typedef bf16 bf16x8 __attribute__((ext_vector_type(8)));
typedef bf16 bf16x4 __attribute__((ext_vector_type(4)));
typedef short s16x4 __attribute__((ext_vector_type(4)));
typedef float f32x4 __attribute__((ext_vector_type(4)));

// 16x16x16 bf16 MFMA (K=16). Carried-forward CDNA2/3 shape, present on gfx950
// (cdna4_isa.md §10). Builtin name is the _1k variant; asm fallback hedges.
#if __has_builtin(__builtin_amdgcn_mfma_f32_16x16x16bf16_1k)
static __device__ __forceinline__ f32x4 mfma16(bf16x4 a, bf16x4 b, f32x4 c) {
    return __builtin_amdgcn_mfma_f32_16x16x16bf16_1k(
        __builtin_bit_cast(s16x4, a), __builtin_bit_cast(s16x4, b), c, 0, 0, 0);
}
#else
static __device__ __forceinline__ f32x4 mfma16(bf16x4 a, bf16x4 b, f32x4 c) {
    f32x4 d;
    asm("v_mfma_f32_16x16x16_bf16 %0, %1, %2, %3"
        : "=v"(d) : "v"(a), "v"(b), "0"(c));
    return d;
}
#endif

// ---------------------------------------------------------------------------
// Fused transpose via LDS (unchanged — measured-OK path).
// ---------------------------------------------------------------------------
#define HS 1160
#define NS 72

__global__ __launch_bounds__(256) void transpose_fused(
    const float* __restrict__ q, const float* __restrict__ k, const float* __restrict__ v,
    bf16* __restrict__ qt, bf16* __restrict__ ktb, bf16* __restrict__ vtT)
{
    __shared__ __attribute__((aligned(16))) bf16 lds[16 * HS];  // 37.1 KB
    int bx = blockIdx.x;
    int tensor = bx >> 9;          // 512 blocks per tensor
    int rr = bx & 511;
    int bg = rr >> 6;
    int tile = rr & 63;
    int n0 = tile * 16;
    int t = threadIdx.x;

    const float* src = (tensor == 0) ? q : (tensor == 1) ? k : v;
    float scale = (tensor == 0) ? QSCALE : 1.0f;
    const float* sb = src + (size_t)bg * N_ * 1024 + (size_t)n0 * 1024;

    int h0 = 4 * (t & 3);          // element j of the float4 has h = h0+j, same d
    int d  = t >> 2;
    int wbase = h0 * HS + d;
#pragma unroll 4
    for (int i = 0; i < 16; ++i) {
        float4 val = ((const float4*)(sb + (size_t)i * 1024))[t];
        bf16* p = &lds[wbase + i * NS];
        p[0]        = (bf16)(val.x * scale);
        p[HS]       = (bf16)(val.y * scale);
        p[2 * HS]   = (bf16)(val.z * scale);
        p[3 * HS]   = (bf16)(val.w * scale);
    }
    __syncthreads();

    if (tensor < 2) {
        bf16* dst = (tensor == 0) ? qt : ktb;
        int n  = (t >> 3) & 15;
        int db = t & 7;
        int hb = t >> 7;
#pragma unroll
        for (int i = 0; i < 8; ++i) {
            int h = 2 * i + hb;
            bf16x8 vv = *(const bf16x8*)(&lds[h * HS + n * NS + db * 8]);
            *(bf16x8*)(dst + (((size_t)(bg * H_ + h)) * N_ + n0 + n) * D_ + db * 8) = vv;
        }
    } else {
        int dd = t & 63;
        int nc = (t >> 6) & 1;
        int hb = t >> 7;
#pragma unroll
        for (int i = 0; i < 8; ++i) {
            int h = 2 * i + hb;
            bf16x8 vv;
#pragma unroll
            for (int jj = 0; jj < 8; ++jj)
                vv[jj] = lds[h * HS + (nc * 8 + jj) * NS + dd];
            *(bf16x8*)(vtT + (((size_t)(bg * H_ + h)) * D_ + dd) * N_ + n0 + nc * 8) = vv;
        }
    }
}

// ---------------------------------------------------------------------------
// Flash v6: swapped-operand QK^T -> S^T in registers -> P^T registers ARE the
// 16x16x16 PV B-frags. P never touches LDS (removes 32 ds_write_b16 + 4
// ds_read_b128 per lane-iter and the dominant bank-conflict source). Bias
// becomes 8x dwordx4 per lane-iter (was 32x dword). p_lds freed -> K/V
// double-buffered in the same 36.9 KB -> ONE barrier per iteration.
// Each wave owns 32 Q-rows (2 col-groups of 16); block = 128 rows; grid 8x128.
// ---------------------------------------------------------------------------
__global__ __launch_bounds__(256, 2) void flash_kernel(
    const bf16* __restrict__ qt, const bf16* __restrict__ kt, const bf16* __restrict__ vtT,
    const float* __restrict__ bias, float* __restrict__ out)
{
    __shared__ __attribute__((aligned(16))) bf16 k_lds[2][MK][72];  // [buf][m][d], chunks swizzled
    __shared__ __attribute__((aligned(16))) bf16 v_lds[2][D_][72];  // [buf][d][m], chunks swizzled

    int tid  = threadIdx.x;
    int w    = tid >> 6;
    int lane = tid & 63;
    int quad = lane >> 4;
    int col  = lane & 15;
    int c3   = col & 3;
    int q4   = quad * 4;

    int bgh = blockIdx.y;
    int n0  = blockIdx.x * 128;
    int g   = (bgh >> 4) & (G_ - 1);       // bgh = (b*G+g)*H + h

    // Q fragments (B-operand now; same per-lane data/loads as before)
    const bf16* qb0 = qt + ((size_t)bgh * N_ + n0 + w * 32 + col) * D_;
    const bf16* qb1 = qb0 + 16 * D_;
    bf16x8 aq00 = *(const bf16x8*)(qb0 + quad * 8);
    bf16x8 aq01 = *(const bf16x8*)(qb0 + 32 + quad * 8);
    bf16x8 aq10 = *(const bf16x8*)(qb1 + quad * 8);
    bf16x8 aq11 = *(const bf16x8*)(qb1 + 32 + quad * 8);

    // acc{grp}[t][r] = out^T[d = t*16 + quad*4 + r][q = n0 + w*32 + grp*16 + col]
    f32x4 acc0[4], acc1[4];
#pragma unroll
    for (int t = 0; t < 4; ++t) { acc0[t] = (f32x4){0,0,0,0}; acc1[t] = (f32x4){0,0,0,0}; }
    float l0 = 0.f, l1 = 0.f;

    // staging: srow = K-row (or V^T d-row), 16-elem chunk j stored at chunk j^(srow&3)
    int srow = tid >> 2;
    int j    = tid & 3;
    int jsw  = (j ^ (srow & 3)) * 16;
    const bf16* kp = kt + (size_t)bgh * N_ * D_ + (size_t)srow * D_ + j * 16;
    const bf16* vp = vtT + ((size_t)bgh * D_ + srow) * N_ + j * 16;

    // per-lane bias row base: this lane's q-row (contiguous in m -> dwordx4)
    const float* bbL0 = bias + (size_t)g * N_ * N_ + (size_t)(n0 + w * 32 + col) * N_;
    const float* bbL1 = bbL0 + (size_t)16 * N_;

    bf16x8 kr0 = *(const bf16x8*)(kp);
    bf16x8 kr1 = *(const bf16x8*)(kp + 8);
    bf16x8 vr0 = *(const bf16x8*)(vp);
    bf16x8 vr1 = *(const bf16x8*)(vp + 8);
    // prologue: stage tile 0 into buf 0
    *(bf16x8*)(&k_lds[0][srow][jsw])     = kr0;
    *(bf16x8*)(&k_lds[0][srow][jsw + 8]) = kr1;
    *(bf16x8*)(&v_lds[0][srow][jsw])     = vr0;
    *(bf16x8*)(&v_lds[0][srow][jsw + 8]) = vr1;

    // swizzled read offsets (16-elem chunk granularity, key = row&3 = col&3)
    int kofs0 = (quad * 8) ^ (c3 << 4);
    int kofs1 = (32 + quad * 8) ^ (c3 << 4);

    for (int it = 0; it < N_ / MK; ++it) {
        int m0  = it * MK;
        int cur = it & 1;
        __syncthreads();   // buf cur writes visible; buf cur^1 no longer read

        if (it + 1 < N_ / MK) {   // register prefetch of next K/V tile
            kp += MK * D_;  vp += MK;
            kr0 = *(const bf16x8*)(kp);
            kr1 = *(const bf16x8*)(kp + 8);
            vr0 = *(const bf16x8*)(vp);
            vr1 = *(const bf16x8*)(vp + 8);
        }

        // bias loads issued early; consumed after the QK MFMAs
        f32x4 bv0[4], bv1[4];
#pragma unroll
        for (int c = 0; c < 4; ++c) {
            bv0[c] = *(const f32x4*)(bbL0 + m0 + c * 16 + q4);
            bv1[c] = *(const f32x4*)(bbL1 + m0 + c * 16 + q4);
        }

        // ---- S^T = K·Q^T per 16-row c-tile, both q-groups (operands swapped) ----
        f32x4 s0[4], s1[4];
        f32x4 z = {0,0,0,0};
#pragma unroll
        for (int c = 0; c < 4; ++c) {
            bf16x8 kb0 = *(const bf16x8*)(&k_lds[cur][c * 16 + col][kofs0]);
            bf16x8 kb1 = *(const bf16x8*)(&k_lds[cur][c * 16 + col][kofs1]);
            s0[c] = __builtin_amdgcn_mfma_f32_16x16x32_bf16(kb0, aq00, z, 0, 0, 0);
            s0[c] = __builtin_amdgcn_mfma_f32_16x16x32_bf16(kb1, aq01, s0[c], 0, 0, 0);
            s1[c] = __builtin_amdgcn_mfma_f32_16x16x32_bf16(kb0, aq10, z, 0, 0, 0);
            s1[c] = __builtin_amdgcn_mfma_f32_16x16x32_bf16(kb1, aq11, s1[c], 0, 0, 0);
        }

        // ---- softmax numerators in-register; p[c][0..3] IS the k16 B-frag ----
        bf16x4 pb0[4], pb1[4];
#pragma unroll
        for (int c = 0; c < 4; ++c) {
#pragma unroll
            for (int r = 0; r < 4; ++r) {
                float p0 = __builtin_amdgcn_exp2f(__builtin_fmaf(-LOG2E, bv0[c][r], s0[c][r]));
                float p1 = __builtin_amdgcn_exp2f(__builtin_fmaf(-LOG2E, bv1[c][r], s1[c][r]));
                l0 += p0;  l1 += p1;
                pb0[c][r] = (bf16)p0;
                pb1[c][r] = (bf16)p1;
            }
        }

        // ---- PV: out^T += V^T·P^T ; V^T A-frags (b64) shared across groups ----
#pragma unroll
        for (int c = 0; c < 4; ++c) {
            int vofs = ((c ^ c3) << 4) + q4;
#pragma unroll
            for (int t = 0; t < 4; ++t) {
                bf16x4 va = *(const bf16x4*)(&v_lds[cur][t * 16 + col][vofs]);
                acc0[t] = mfma16(va, pb0[c], acc0[t]);
                acc1[t] = mfma16(va, pb1[c], acc1[t]);
            }
        }

        // stage next tile into the other buffer (safe: everyone passed this
        // iteration's barrier, so nobody still reads buf cur^1)
        if (it + 1 < N_ / MK) {
            *(bf16x8*)(&k_lds[cur ^ 1][srow][jsw])     = kr0;
            *(bf16x8*)(&k_lds[cur ^ 1][srow][jsw + 8]) = kr1;
            *(bf16x8*)(&v_lds[cur ^ 1][srow][jsw])     = vr0;
            *(bf16x8*)(&v_lds[cur ^ 1][srow][jsw + 8]) = vr1;
        }
    }

    // ---- epilogue: l lives per-quad-partition of m; sum across quads ----
    l0 += __shfl_xor(l0, 16, 64);
    l0 += __shfl_xor(l0, 32, 64);
    l1 += __shfl_xor(l1, 16, 64);
    l1 += __shfl_xor(l1, 32, 64);
    float inv0 = 1.0f / l0, inv1 = 1.0f / l1;

    float* ob0 = out + ((size_t)bgh * N_ + n0 + w * 32 + col) * D_ + q4;
    float* ob1 = ob0 + (size_t)16 * D_;
#pragma unroll
    for (int t = 0; t < 4; ++t) {
        f32x4 o0 = acc0[t] * inv0;
        f32x4 o1 = acc1[t] * inv1;
        *(f32x4*)(ob0 + t * 16) = o0;
        *(f32x4*)(ob1 + t * 16) = o1;
    }
}

// ---------------------------------------------------------------------------
// Fallback (only if ws_size < 50.3MB): naive fp32, one block per (bgh,n) row.
// ---------------------------------------------------------------------------
__global__ __launch_bounds__(256) void naive_kernel(
    const float* __restrict__ q, const float* __restrict__ k,
    const float* __restrict__ v, const float* __restrict__ bias,
    float* __restrict__ out)
{
    __shared__ float sc[N_];
    __shared__ float red[256];
    __shared__ float qrow[64];
    int n = blockIdx.x;
    int bgh = blockIdx.y;
    int bg = bgh >> 4, h = bgh & 15;
    int g = bg & (G_ - 1);
    int tid = threadIdx.x;
    const float* qr = q + ((size_t)(bg * N_ + n)) * 1024;
    if (tid < 64) qrow[tid] = qr[tid * 16 + h];
    __syncthreads();
    const float* bb = bias + (size_t)g * N_ * N_ + (size_t)n * N_;
    for (int m = tid; m < N_; m += 256) {
        const float* kr = k + ((size_t)(bg * N_ + m)) * 1024 + h;
        float dot = 0.f;
        for (int d = 0; d < 64; ++d) dot += qrow[d] * kr[d * 16];
        sc[m] = dot * 0.125f - bb[m];
    }
    __syncthreads();
    float mx = -INFINITY;
    for (int m = tid; m < N_; m += 256) mx = fmaxf(mx, sc[m]);
    red[tid] = mx; __syncthreads();
    for (int s = 128; s > 0; s >>= 1) {
        if (tid < s) red[tid] = fmaxf(red[tid], red[tid + s]);
        __syncthreads();
    }
    float M = red[0]; __syncthreads();
    float sum = 0.f;
    for (int m = tid; m < N_; m += 256) { float e = __expf(sc[m] - M); sc[m] = e; sum += e; }
    red[tid] = sum; __syncthreads();
    for (int s = 128; s > 0; s >>= 1) {
        if (tid < s) red[tid] += red[tid + s];
        __syncthreads();
    }
    float L = red[0]; __syncthreads();
    int d = tid & 63, quarter = tid >> 6;
    float acc = 0.f;
    const float* vb = v + (size_t)bg * N_ * 1024 + d * 16 + h;
    for (int m = quarter * 256; m < quarter * 256 + 256; ++m) acc += sc[m] * vb[(size_t)m * 1024];
    red[tid] = acc; __syncthreads();
    if (tid < 64) {
        float o = (red[tid] + red[tid + 64] + red[tid + 128] + red[tid + 192]) / L;
        out[((size_t)bgh * N_ + n) * 64 + d] = o;
    }
}

extern "C" void kernel_launch(void* const* d_in, const int* in_sizes, int n_in,
                              void* d_out, int out_size, void* d_ws, size_t ws_size,
                              hipStream_t stream) {
    const float* q    = (const float*)d_in[0];
    const float* k    = (const float*)d_in[1];
    const float* v    = (const float*)d_in[2];
    const float* bias = (const float*)d_in[3];
    float* out = (float*)d_out;

    const size_t elems = (size_t)BGH_ * N_ * D_;   // 8388608
    const size_t need  = 3 * elems * sizeof(bf16); // 50.3 MB

    if (ws_size >= need) {
        bf16* qt  = (bf16*)d_ws;
        bf16* ktb = qt + elems;
        bf16* vtT = ktb + elems;
        transpose_fused<<<3 * 512, 256, 0, stream>>>(q, k, v, qt, ktb, vtT);
        dim3 grid(N_ / 128, BGH_);
        flash_kernel<<<grid, 256, 0, stream>>>(qt, ktb, vtT, bias, out);
    } else {
        dim3 grid(N_, BGH_);
        naive_kernel<<<grid, 256, 0, stream>>>(q, k, v, bias, out);
    }
}

// Round 2
// 237.055 us; speedup vs baseline: 1.1288x; 1.1288x over previous
//
#include <hip/hip_runtime.h>
#include <hip/hip_bf16.h>
#include <math.h>

// Problem constants (GenNeuronStates): B=2,G=4,N=1024,H=16,dq=dv=64
#define B_ 2
#define G_ 4
#define N_ 1024
#define H_ 16
#define D_ 64
#define BG_ (B_*G_)
#define BGH_ (B_*G_*H_)
#define MK 64   // K/V tile rows per flash iteration
#define LOG2E 1.44269504f
#define QSCALE (0.125f * LOG2E)   // folded into Q during transpose

typedef __bf16 bf16;
typedef bf16 bf16x8 __attribute__((ext_vector_type(8)));
typedef bf16 bf16x2 __attribute__((ext_vector_type(2)));
typedef float f32x4 __attribute__((ext_vector_type(4)));
typedef float f32x16 __attribute__((ext_vector_type(16)));
typedef int i32x4 __attribute__((ext_vector_type(4)));
typedef unsigned u32x2 __attribute__((ext_vector_type(2)));

static __device__ __forceinline__ f32x16 mfma32(bf16x8 a, bf16x8 b, f32x16 c) {
    return __builtin_amdgcn_mfma_f32_32x32x16_bf16(a, b, c, 0, 0, 0);
}

// pack two f32 -> one dword of 2 bf16 (compiler emits v_cvt_pk_bf16_f32)
static __device__ __forceinline__ unsigned pk2(float a, float b) {
    bf16x2 t; t[0] = (bf16)a; t[1] = (bf16)b;
    return __builtin_bit_cast(unsigned, t);
}

// permlane32_swap: a' = {a.lo, b.lo}, b' = {a.hi, b.hi}  (halves = lanes 0-31 / 32-63)
static __device__ __forceinline__ void pl32swap(unsigned& a, unsigned& b, int hi) {
#if __has_builtin(__builtin_amdgcn_permlane32_swap)
    u32x2 r = __builtin_amdgcn_permlane32_swap(a, b, false, false);
    a = r[0]; b = r[1];
    (void)hi;
#else
    unsigned ax = (unsigned)__shfl_xor((int)a, 32, 64);
    unsigned bx = (unsigned)__shfl_xor((int)b, 32, 64);
    unsigned na = hi ? bx : a;
    unsigned nb = hi ? b : ax;
    a = na; b = nb;
#endif
}

// ---------------------------------------------------------------------------
// Fused transpose via LDS (unchanged — measured-OK path).
// ---------------------------------------------------------------------------
#define HS 1160
#define NS 72

__global__ __launch_bounds__(256) void transpose_fused(
    const float* __restrict__ q, const float* __restrict__ k, const float* __restrict__ v,
    bf16* __restrict__ qt, bf16* __restrict__ ktb, bf16* __restrict__ vtT)
{
    __shared__ __attribute__((aligned(16))) bf16 lds[16 * HS];  // 37.1 KB
    int bx = blockIdx.x;
    int tensor = bx >> 9;          // 512 blocks per tensor
    int rr = bx & 511;
    int bg = rr >> 6;
    int tile = rr & 63;
    int n0 = tile * 16;
    int t = threadIdx.x;

    const float* src = (tensor == 0) ? q : (tensor == 1) ? k : v;
    float scale = (tensor == 0) ? QSCALE : 1.0f;
    const float* sb = src + (size_t)bg * N_ * 1024 + (size_t)n0 * 1024;

    int h0 = 4 * (t & 3);          // element j of the float4 has h = h0+j, same d
    int d  = t >> 2;
    int wbase = h0 * HS + d;
#pragma unroll 4
    for (int i = 0; i < 16; ++i) {
        float4 val = ((const float4*)(sb + (size_t)i * 1024))[t];
        bf16* p = &lds[wbase + i * NS];
        p[0]        = (bf16)(val.x * scale);
        p[HS]       = (bf16)(val.y * scale);
        p[2 * HS]   = (bf16)(val.z * scale);
        p[3 * HS]   = (bf16)(val.w * scale);
    }
    __syncthreads();

    if (tensor < 2) {
        bf16* dst = (tensor == 0) ? qt : ktb;
        int n  = (t >> 3) & 15;
        int db = t & 7;
        int hb = t >> 7;
#pragma unroll
        for (int i = 0; i < 8; ++i) {
            int h = 2 * i + hb;
            bf16x8 vv = *(const bf16x8*)(&lds[h * HS + n * NS + db * 8]);
            *(bf16x8*)(dst + (((size_t)(bg * H_ + h)) * N_ + n0 + n) * D_ + db * 8) = vv;
        }
    } else {
        int dd = t & 63;
        int nc = (t >> 6) & 1;
        int hb = t >> 7;
#pragma unroll
        for (int i = 0; i < 8; ++i) {
            int h = 2 * i + hb;
            bf16x8 vv;
#pragma unroll
            for (int jj = 0; jj < 8; ++jj)
                vv[jj] = lds[h * HS + (nc * 8 + jj) * NS + dd];
            *(bf16x8*)(vtT + (((size_t)(bg * H_ + h)) * D_ + dd) * N_ + n0 + nc * 8) = vv;
        }
    }
}

// ---------------------------------------------------------------------------
// Flash v7: 32x32 swapped-operand structure (guide §B / T12).
//   S^T = mfma_32x32x16(K-frag, Q-frag) chained over d (4 per 32-k tile).
//   P^T stays in registers: cvt_pk pairs + permlane32_swap -> PV B-frags.
//   PV: O^T += mfma_32x32x16(V^T-frag, P^T-frag), 8 per iter.
//   Bias: coalesced global -> per-wave LDS transpose buffer (granule swizzle
//   pos=(g+2r)&15), loaded one iter ahead; read back as f32x4 per s-quad.
//   K/V double-buffered, ONE barrier per iteration. LDS 71.7KB -> 2 blocks/CU.
// ---------------------------------------------------------------------------
__global__ __launch_bounds__(256, 2) void flash_kernel(
    const bf16* __restrict__ qt, const bf16* __restrict__ kt, const bf16* __restrict__ vtT,
    const float* __restrict__ bias, float* __restrict__ out)
{
    __shared__ __attribute__((aligned(16))) bf16 k_lds[2][MK][72];   // [buf][m][d], 16e chunks swizzled
    __shared__ __attribute__((aligned(16))) bf16 v_lds[2][D_][72];   // [buf][d][m], 16e chunks swizzled
    __shared__ __attribute__((aligned(16))) float bias_lds[4][32][68]; // per-wave [qrow][m], granule swz

    int tid  = threadIdx.x;
    int w    = tid >> 6;
    int lane = tid & 63;
    int hi   = lane >> 5;
    int q31  = lane & 31;
    int key  = (q31 & 3) << 4;     // XOR key for 16-elem chunk swizzle (k/v frags)

    int bgh = blockIdx.y;
    int n0  = blockIdx.x * 128;
    int g   = (bgh >> 4) & (G_ - 1);   // bgh = (b*G+g)*H + h

    // Q B-frags (loop-invariant): B[k=c*16+hi*8+j][n=q31] = Q[q31][d] -> contiguous
    const bf16* qb_base = qt + ((size_t)bgh * N_ + n0 + w * 32 + q31) * D_ + hi * 8;
    bf16x8 qb[4];
#pragma unroll
    for (int c = 0; c < 4; ++c) qb[c] = *(const bf16x8*)(qb_base + c * 16);

    f32x16 acc0 = {0,0,0,0,0,0,0,0,0,0,0,0,0,0,0,0};
    f32x16 acc1 = {0,0,0,0,0,0,0,0,0,0,0,0,0,0,0,0};
    float l = 0.f;

    // K/V staging: srow = K-row (or V^T d-row), chunk j stored at j^(srow&3)
    int srow = tid >> 2;
    int j    = tid & 3;
    int jsw  = (j ^ (srow & 3)) * 16;
    const bf16* kp = kt + (size_t)bgh * N_ * D_ + (size_t)srow * D_ + j * 16;
    const bf16* vp = vtT + ((size_t)bgh * D_ + srow) * N_ + j * 16;

    // bias staging: lane -> row brow (0..31), col half bh2*32; coalesced f32x4 x8
    int brow = lane >> 1;
    int bh2  = lane & 1;
    const float* bbL = bias + (size_t)g * N_ * N_ + (size_t)(n0 + w * 32 + brow) * N_ + bh2 * 32;

    // ---- prologue: K/V tile 0 + bias tile 0 ----
    bf16x8 kr0 = *(const bf16x8*)(kp);
    bf16x8 kr1 = *(const bf16x8*)(kp + 8);
    bf16x8 vr0 = *(const bf16x8*)(vp);
    bf16x8 vr1 = *(const bf16x8*)(vp + 8);
    f32x4 bnx[8];
#pragma unroll
    for (int kk = 0; kk < 8; ++kk) bnx[kk] = *(const f32x4*)(bbL + kk * 4);

    *(bf16x8*)(&k_lds[0][srow][jsw])     = kr0;
    *(bf16x8*)(&k_lds[0][srow][jsw + 8]) = kr1;
    *(bf16x8*)(&v_lds[0][srow][jsw])     = vr0;
    *(bf16x8*)(&v_lds[0][srow][jsw + 8]) = vr1;
#pragma unroll
    for (int kk = 0; kk < 8; ++kk) {
        int pos = ((bh2 * 8 + kk) + 2 * brow) & 15;
        *(f32x4*)(&bias_lds[w][brow][pos * 4]) = bnx[kk];
    }

    for (int it = 0; it < N_ / MK; ++it) {
        int  cur  = it & 1;
        bool more = (it + 1 < N_ / MK);
        __syncthreads();   // K/V buf cur ready; buf cur^1 free for staging

        if (more) {        // global prefetch of next K/V tile + next bias tile
            kp += MK * D_;  vp += MK;
            kr0 = *(const bf16x8*)(kp);
            kr1 = *(const bf16x8*)(kp + 8);
            vr0 = *(const bf16x8*)(vp);
            vr1 = *(const bf16x8*)(vp + 8);
#pragma unroll
            for (int kk = 0; kk < 8; ++kk)
                bnx[kk] = *(const f32x4*)(bbL + (it + 1) * MK + kk * 4);
        }

        // bias for CURRENT iter from per-wave LDS (written last iter / prologue)
        // bv[t][u][e] = bias[qrow=q31][m = it*64 + t*32 + 8u + 4hi + e]
        f32x4 bv[2][4];
#pragma unroll
        for (int t = 0; t < 2; ++t)
#pragma unroll
            for (int u = 0; u < 4; ++u) {
                int pos = ((t * 8 + 2 * u + hi) + 2 * q31) & 15;
                bv[t][u] = *(const f32x4*)(&bias_lds[w][q31][pos * 4]);
            }

        // ---- QK: S^T = K·Q^T, two 32-row tiles, K-dim chained over 4 d-chunks ----
        f32x16 s0 = {0,0,0,0,0,0,0,0,0,0,0,0,0,0,0,0};
        f32x16 s1 = {0,0,0,0,0,0,0,0,0,0,0,0,0,0,0,0};
        __builtin_amdgcn_s_setprio(1);
#pragma unroll
        for (int c = 0; c < 4; ++c) {
            bf16x8 kb0 = *(const bf16x8*)(&k_lds[cur][q31]     [((c << 4) ^ key) + hi * 8]);
            bf16x8 kb1 = *(const bf16x8*)(&k_lds[cur][32 + q31][((c << 4) ^ key) + hi * 8]);
            s0 = mfma32(kb0, qb[c], s0);
            s1 = mfma32(kb1, qb[c], s1);
        }
        __builtin_amdgcn_s_setprio(0);

        // ---- softmax numerators in-register + bf16 pack ----
        // reg r of s_t: krow_local = (r&3) + 8*(r>>2) + 4*hi  (m74/m101 layout)
        unsigned wa[2][4], wb[2][4];
#pragma unroll
        for (int t = 0; t < 2; ++t) {
#pragma unroll
            for (int u = 0; u < 4; ++u) {
                const f32x16& s = t ? s1 : s0;
                float p0 = __builtin_amdgcn_exp2f(__builtin_fmaf(-LOG2E, bv[t][u][0], s[4*u+0]));
                float p1 = __builtin_amdgcn_exp2f(__builtin_fmaf(-LOG2E, bv[t][u][1], s[4*u+1]));
                float p2 = __builtin_amdgcn_exp2f(__builtin_fmaf(-LOG2E, bv[t][u][2], s[4*u+2]));
                float p3 = __builtin_amdgcn_exp2f(__builtin_fmaf(-LOG2E, bv[t][u][3], s[4*u+3]));
                l += (p0 + p1) + (p2 + p3);
                wa[t][u] = pk2(p0, p1);
                wb[t][u] = pk2(p2, p3);
            }
        }

        // write NEXT bias tile into per-wave LDS (current values already in regs)
        if (more) {
#pragma unroll
            for (int kk = 0; kk < 8; ++kk) {
                int pos = ((bh2 * 8 + kk) + 2 * brow) & 15;
                *(f32x4*)(&bias_lds[w][brow][pos * 4]) = bnx[kk];
            }
        }

        // ---- cross-half exchange: one swap fills word0+word2 (T12) ----
#pragma unroll
        for (int t = 0; t < 2; ++t) {
            pl32swap(wa[t][0], wa[t][1], hi);
            pl32swap(wb[t][0], wb[t][1], hi);
            pl32swap(wa[t][2], wa[t][3], hi);
            pl32swap(wb[t][2], wb[t][3], hi);
        }

        // ---- PV: O^T += V^T · P^T, 4 k-chunks x 2 d-blocks ----
        __builtin_amdgcn_s_setprio(1);
#pragma unroll
        for (int t = 0; t < 2; ++t)
#pragma unroll
            for (int c01 = 0; c01 < 2; ++c01) {
                int kc = t * 2 + c01;
                i32x4 bwi = { (int)wa[t][2*c01], (int)wb[t][2*c01],
                              (int)wa[t][2*c01+1], (int)wb[t][2*c01+1] };
                bf16x8 pb = __builtin_bit_cast(bf16x8, bwi);
                bf16x8 va0 = *(const bf16x8*)(&v_lds[cur][q31]     [((kc << 4) ^ key) + hi * 8]);
                bf16x8 va1 = *(const bf16x8*)(&v_lds[cur][32 + q31][((kc << 4) ^ key) + hi * 8]);
                acc0 = mfma32(va0, pb, acc0);
                acc1 = mfma32(va1, pb, acc1);
            }
        __builtin_amdgcn_s_setprio(0);

        // stage next K/V tile (safe: everyone passed this iteration's barrier)
        if (more) {
            int nxt = cur ^ 1;
            *(bf16x8*)(&k_lds[nxt][srow][jsw])     = kr0;
            *(bf16x8*)(&k_lds[nxt][srow][jsw + 8]) = kr1;
            *(bf16x8*)(&v_lds[nxt][srow][jsw])     = vr0;
            *(bf16x8*)(&v_lds[nxt][srow][jsw + 8]) = vr1;
        }
    }

    // ---- epilogue: l split across hi-halves only; one shfl; vectorized store ----
    l += __shfl_xor(l, 32, 64);
    float inv = 1.0f / l;

    float* ob = out + ((size_t)bgh * N_ + n0 + w * 32 + q31) * D_ + hi * 4;
#pragma unroll
    for (int td = 0; td < 2; ++td) {
        const f32x16& a = td ? acc1 : acc0;
#pragma unroll
        for (int u = 0; u < 4; ++u) {
            f32x4 o = { a[4*u+0] * inv, a[4*u+1] * inv, a[4*u+2] * inv, a[4*u+3] * inv };
            *(f32x4*)(ob + td * 32 + u * 8) = o;
        }
    }
}

// ---------------------------------------------------------------------------
// Fallback (only if ws_size < 50.3MB): naive fp32, one block per (bgh,n) row.
// ---------------------------------------------------------------------------
__global__ __launch_bounds__(256) void naive_kernel(
    const float* __restrict__ q, const float* __restrict__ k,
    const float* __restrict__ v, const float* __restrict__ bias,
    float* __restrict__ out)
{
    __shared__ float sc[N_];
    __shared__ float red[256];
    __shared__ float qrow[64];
    int n = blockIdx.x;
    int bgh = blockIdx.y;
    int bg = bgh >> 4, h = bgh & 15;
    int g = bg & (G_ - 1);
    int tid = threadIdx.x;
    const float* qr = q + ((size_t)(bg * N_ + n)) * 1024;
    if (tid < 64) qrow[tid] = qr[tid * 16 + h];
    __syncthreads();
    const float* bb = bias + (size_t)g * N_ * N_ + (size_t)n * N_;
    for (int m = tid; m < N_; m += 256) {
        const float* kr = k + ((size_t)(bg * N_ + m)) * 1024 + h;
        float dot = 0.f;
        for (int d = 0; d < 64; ++d) dot += qrow[d] * kr[d * 16];
        sc[m] = dot * 0.125f - bb[m];
    }
    __syncthreads();
    float mx = -INFINITY;
    for (int m = tid; m < N_; m += 256) mx = fmaxf(mx, sc[m]);
    red[tid] = mx; __syncthreads();
    for (int s = 128; s > 0; s >>= 1) {
        if (tid < s) red[tid] = fmaxf(red[tid], red[tid + s]);
        __syncthreads();
    }
    float M = red[0]; __syncthreads();
    float sum = 0.f;
    for (int m = tid; m < N_; m += 256) { float e = __expf(sc[m] - M); sc[m] = e; sum += e; }
    red[tid] = sum; __syncthreads();
    for (int s = 128; s > 0; s >>= 1) {
        if (tid < s) red[tid] += red[tid + s];
        __syncthreads();
    }
    float L = red[0]; __syncthreads();
    int d = tid & 63, quarter = tid >> 6;
    float acc = 0.f;
    const float* vb = v + (size_t)bg * N_ * 1024 + d * 16 + h;
    for (int m = quarter * 256; m < quarter * 256 + 256; ++m) acc += sc[m] * vb[(size_t)m * 1024];
    red[tid] = acc; __syncthreads();
    if (tid < 64) {
        float o = (red[tid] + red[tid + 64] + red[tid + 128] + red[tid + 192]) / L;
        out[((size_t)bgh * N_ + n) * 64 + d] = o;
    }
}

extern "C" void kernel_launch(void* const* d_in, const int* in_sizes, int n_in,
                              void* d_out, int out_size, void* d_ws, size_t ws_size,
                              hipStream_t stream) {
    const float* q    = (const float*)d_in[0];
    const float* k    = (const float*)d_in[1];
    const float* v    = (const float*)d_in[2];
    const float* bias = (const float*)d_in[3];
    float* out = (float*)d_out;

    const size_t elems = (size_t)BGH_ * N_ * D_;   // 8388608
    const size_t need  = 3 * elems * sizeof(bf16); // 50.3 MB

    if (ws_size >= need) {
        bf16* qt  = (bf16*)d_ws;
        bf16* ktb = qt + elems;
        bf16* vtT = ktb + elems;
        transpose_fused<<<3 * 512, 256, 0, stream>>>(q, k, v, qt, ktb, vtT);
        dim3 grid(N_ / 128, BGH_);
        flash_kernel<<<grid, 256, 0, stream>>>(qt, ktb, vtT, bias, out);
    } else {
        dim3 grid(N_, BGH_);
        naive_kernel<<<grid, 256, 0, stream>>>(q, k, v, bias, out);
    }
}

// Round 3
// 213.669 us; speedup vs baseline: 1.2524x; 1.1095x over previous
//
#include <hip/hip_runtime.h>
#include <hip/hip_bf16.h>
#include <math.h>

// Problem constants (GenNeuronStates): B=2,G=4,N=1024,H=16,dq=dv=64
#define B_ 2
#define G_ 4
#define N_ 1024
#define H_ 16
#define D_ 64
#define BG_ (B_*G_)
#define BGH_ (B_*G_*H_)
#define MK 64   // K/V tile rows per flash iteration
#define LOG2E 1.44269504f
#define QSCALE (0.125f * LOG2E)   // folded into Q during transpose

typedef __bf16 bf16;
typedef bf16 bf16x8 __attribute__((ext_vector_type(8)));
typedef bf16 bf16x2 __attribute__((ext_vector_type(2)));
typedef float f32x4 __attribute__((ext_vector_type(4)));
typedef float f32x16 __attribute__((ext_vector_type(16)));
typedef int i32x4 __attribute__((ext_vector_type(4)));
typedef unsigned u32x2 __attribute__((ext_vector_type(2)));

static __device__ __forceinline__ f32x16 mfma32(bf16x8 a, bf16x8 b, f32x16 c) {
    return __builtin_amdgcn_mfma_f32_32x32x16_bf16(a, b, c, 0, 0, 0);
}

// pack two f32 -> one dword of 2 bf16 (compiler emits v_cvt_pk_bf16_f32)
static __device__ __forceinline__ unsigned pk2(float a, float b) {
    bf16x2 t; t[0] = (bf16)a; t[1] = (bf16)b;
    return __builtin_bit_cast(unsigned, t);
}

// permlane32_swap: a' = {a.lo, b.lo}, b' = {a.hi, b.hi}  (halves = lanes 0-31 / 32-63)
static __device__ __forceinline__ void pl32swap(unsigned& a, unsigned& b, int hi) {
#if __has_builtin(__builtin_amdgcn_permlane32_swap)
    u32x2 r = __builtin_amdgcn_permlane32_swap(a, b, false, false);
    a = r[0]; b = r[1];
    (void)hi;
#else
    unsigned ax = (unsigned)__shfl_xor((int)a, 32, 64);
    unsigned bx = (unsigned)__shfl_xor((int)b, 32, 64);
    unsigned na = hi ? bx : a;
    unsigned nb = hi ? b : ax;
    a = na; b = nb;
#endif
}

// async global->LDS, 16B per lane; dest = wave-uniform base + lane*16 (m104)
static __device__ __forceinline__ void gll16(const void* gsrc, void* ldst, int lane) {
#if __has_builtin(__builtin_amdgcn_global_load_lds)
    (void)lane;
    __builtin_amdgcn_global_load_lds((const __attribute__((address_space(1))) void*)gsrc,
                                     (__attribute__((address_space(3))) void*)ldst, 16, 0, 0);
#else
    *(bf16x8*)((bf16*)ldst + lane * 8) = *(const bf16x8*)((const bf16*)gsrc);
#endif
}

// ---------------------------------------------------------------------------
// Fused prep pass.
//   bx < 1536 : Q/K/V transpose (Q/K branches unchanged; V now writes the
//               16-chunked vtT16[bgh][n/16][d][16] layout -> coalesced stores)
//   bx >= 1536: bias blocked-transpose biasX[g][m/4][q][4] (f32x4-granular)
// ---------------------------------------------------------------------------
#define HS 1160
#define NS 72

__global__ __launch_bounds__(256) void transpose_fused(
    const float* __restrict__ q, const float* __restrict__ k, const float* __restrict__ v,
    const float* __restrict__ bias,
    bf16* __restrict__ qt, bf16* __restrict__ ktb, bf16* __restrict__ vtT16,
    float* __restrict__ biasX)
{
    __shared__ __attribute__((aligned(16))) bf16 lds[16 * HS];  // 37.1 KB (reused by bias branch)
    int bx = blockIdx.x;
    int t = threadIdx.x;

    if (bx >= 3 * 512) {
        // ---- bias blocked transpose: biasX[((g*256+mb)*1024+q)*4+mo] = bias[g][q][4mb+mo]
        int idx = bx - 3 * 512;
        int gg  = idx >> 8;            // 0..3
        int tl  = idx & 255;
        int q0  = (tl >> 4) * 64;
        int m0  = (tl & 15) * 64;
        float* ldsF = (float*)lds;     // [64][68] f32, 17.4 KB

        int mi = t & 15, qr = t >> 4;
#pragma unroll
        for (int rr = 0; rr < 4; ++rr) {
            int row = qr + rr * 16;
            f32x4 val = *(const f32x4*)(bias + ((size_t)(gg * N_ + q0 + row) * N_ + m0 + 4 * mi));
            *(f32x4*)(&ldsF[row * 68 + 4 * mi]) = val;
        }
        __syncthreads();
        int qr2 = t & 63, mb0 = t >> 6;
#pragma unroll
        for (int kk = 0; kk < 4; ++kk) {
            int mbi = mb0 + kk * 4;    // 0..15
            f32x4 vv = *(const f32x4*)(&ldsF[qr2 * 68 + 4 * mbi]);
            *(f32x4*)(biasX + (((size_t)gg * 256 + m0 / 4 + mbi) * N_ + q0 + qr2) * 4) = vv;
        }
        return;
    }

    int tensor = bx >> 9;          // 512 blocks per tensor
    int rr = bx & 511;
    int bg = rr >> 6;
    int tile = rr & 63;
    int n0 = tile * 16;

    const float* src = (tensor == 0) ? q : (tensor == 1) ? k : v;
    float scale = (tensor == 0) ? QSCALE : 1.0f;
    const float* sb = src + (size_t)bg * N_ * 1024 + (size_t)n0 * 1024;

    int h0 = 4 * (t & 3);          // element j of the float4 has h = h0+j, same d
    int d  = t >> 2;
    int wbase = h0 * HS + d;
#pragma unroll 4
    for (int i = 0; i < 16; ++i) {
        float4 val = ((const float4*)(sb + (size_t)i * 1024))[t];
        bf16* p = &lds[wbase + i * NS];
        p[0]        = (bf16)(val.x * scale);
        p[HS]       = (bf16)(val.y * scale);
        p[2 * HS]   = (bf16)(val.z * scale);
        p[3 * HS]   = (bf16)(val.w * scale);
    }
    __syncthreads();

    if (tensor < 2) {
        bf16* dst = (tensor == 0) ? qt : ktb;
        int n  = (t >> 3) & 15;
        int db = t & 7;
        int hb = t >> 7;
#pragma unroll
        for (int i = 0; i < 8; ++i) {
            int h = 2 * i + hb;
            bf16x8 vv = *(const bf16x8*)(&lds[h * HS + n * NS + db * 8]);
            *(bf16x8*)(dst + (((size_t)(bg * H_ + h)) * N_ + n0 + n) * D_ + db * 8) = vv;
        }
    } else {
        // V -> vtT16[bgh][nchunk=tile][d][16]; lanes at consecutive d -> 2KB runs
        int dd = t & 63;
        int hb = t >> 6;           // 0..3
#pragma unroll
        for (int i = 0; i < 4; ++i) {
            int h = hb * 4 + i;
            bf16x8 v0, v1;
#pragma unroll
            for (int jj = 0; jj < 8; ++jj) v0[jj] = lds[h * HS + jj * NS + dd];
#pragma unroll
            for (int jj = 0; jj < 8; ++jj) v1[jj] = lds[h * HS + (8 + jj) * NS + dd];
            bf16* dst = vtT16 + (((size_t)(bg * H_ + h) * 64 + tile) * D_ + dd) * 16;
            *(bf16x8*)dst       = v0;
            *(bf16x8*)(dst + 8) = v1;
        }
    }
}

// ---------------------------------------------------------------------------
// Flash v8: v7's 32x32 swapped-operand math, restructured for occupancy:
//  - bias_lds GONE: biasX gives each lane its S^T reg-quad bias as one
//    coalesced f32x4 (8 VMEM/lane-iter), prefetched ~1/2 iter ahead.
//  - K/V staged via global_load_lds (16B), linear LDS + source-side swizzle
//    chunk' = chunk ^ (row&7)  (read side XORs the same key) — rule #21.
//  - LDS 32KB, launch_bounds(256,3) -> 3-4 blocks/CU (was 2).
//  - double-buffered, ONE barrier/iter; the compiler's pre-barrier vmcnt(0)
//    drain is the publish point for the async loads (issued a full iter early).
// ---------------------------------------------------------------------------
__global__ __launch_bounds__(256, 3) void flash_kernel(
    const bf16* __restrict__ qt, const bf16* __restrict__ kt, const bf16* __restrict__ vtT16,
    const float* __restrict__ biasX, float* __restrict__ out)
{
    __shared__ __attribute__((aligned(16))) bf16 k_lds[2][MK][D_];  // [buf][m][d] linear
    __shared__ __attribute__((aligned(16))) bf16 v_lds[2][D_][MK];  // [buf][d][m] linear

    int tid  = threadIdx.x;
    int w    = tid >> 6;
    int lane = tid & 63;
    int hi   = lane >> 5;
    int q31  = lane & 31;
    int key8 = (q31 & 7) << 3;     // elem-XOR key for frag reads (8-elem granule)
    int hi8  = hi << 3;

    int bgh = blockIdx.y;
    int n0  = blockIdx.x * 128;
    int g   = (bgh >> 4) & (G_ - 1);   // bgh = (b*G+g)*H + h

    // Q B-frags (loop-invariant)
    const bf16* qb_base = qt + ((size_t)bgh * N_ + n0 + w * 32 + q31) * D_ + hi * 8;
    bf16x8 qb[4];
#pragma unroll
    for (int c = 0; c < 4; ++c) qb[c] = *(const bf16x8*)(qb_base + c * 16);

    f32x16 acc0 = {0,0,0,0,0,0,0,0,0,0,0,0,0,0,0,0};
    f32x16 acc1 = {0,0,0,0,0,0,0,0,0,0,0,0,0,0,0,0};
    float l = 0.f;

    // ---- staging geometry: waves 0,1 stage K rows wrow..wrow+31; waves 2,3 stage V
    int rloc = lane >> 3;              // 0..7
    int c16  = lane & 7;               // 16B chunk within 128B row
    int csw  = c16 ^ rloc;             // source chunk (row&7 == rloc for all instrs)
    bool isK = (w < 2);
    int wrow = (w & 1) * 32;
    const bf16* ksrc = kt + (size_t)bgh * N_ * D_ + (size_t)(wrow + rloc) * D_ + csw * 8;
    const bf16* vsrc = vtT16 + (((size_t)bgh * 64 + (csw >> 1)) * D_ + (wrow + rloc)) * 16 + (csw & 1) * 8;

    // ---- bias: lane's q-row column of biasX; quad (it,t,u) at mb*4096 floats
    const float* bb = biasX + (size_t)g * (256u * 1024 * 4) + (size_t)(n0 + w * 32 + q31) * 4;

    // ---- prologue: stage tile 0 + bias tile 0 ----
    if (isK) {
#pragma unroll
        for (int i = 0; i < 4; ++i) gll16(ksrc + (size_t)i * 8 * D_, &k_lds[0][wrow + i * 8][0], lane);
    } else {
#pragma unroll
        for (int i = 0; i < 4; ++i) gll16(vsrc + (size_t)i * 128, &v_lds[0][wrow + i * 8][0], lane);
    }
    f32x4 bnx[8];
#pragma unroll
    for (int tt = 0; tt < 2; ++tt)
#pragma unroll
        for (int u = 0; u < 4; ++u)
            bnx[tt * 4 + u] = *(const f32x4*)(bb + (size_t)(tt * 8 + 2 * u + hi) * 4096);

    for (int it = 0; it < N_ / MK; ++it) {
        int  cur  = it & 1;
        bool more = (it + 1 < N_ / MK);
        __syncthreads();   // drains vmcnt -> buf cur published; buf cur^1 free

        if (more) {        // async-stage next tile (fire-and-forget, drained at next barrier)
            int nxt = cur ^ 1;
            if (isK) {
                const bf16* ks = ksrc + (size_t)(it + 1) * MK * D_;
#pragma unroll
                for (int i = 0; i < 4; ++i) gll16(ks + (size_t)i * 8 * D_, &k_lds[nxt][wrow + i * 8][0], lane);
            } else {
                const bf16* vs = vsrc + (size_t)(it + 1) * 4096;
#pragma unroll
                for (int i = 0; i < 4; ++i) gll16(vs + (size_t)i * 128, &v_lds[nxt][wrow + i * 8][0], lane);
            }
        }

        // ---- QK: S^T = K·Q^T, two 32-row tiles, chained over 4 d-chunks ----
        f32x16 s0 = {0,0,0,0,0,0,0,0,0,0,0,0,0,0,0,0};
        f32x16 s1 = {0,0,0,0,0,0,0,0,0,0,0,0,0,0,0,0};
        __builtin_amdgcn_s_setprio(1);
#pragma unroll
        for (int c = 0; c < 4; ++c) {
            int off = ((c << 4) | hi8) ^ key8;
            bf16x8 kb0 = *(const bf16x8*)(&k_lds[cur][q31][off]);
            bf16x8 kb1 = *(const bf16x8*)(&k_lds[cur][32 + q31][off]);
            s0 = mfma32(kb0, qb[c], s0);
            s1 = mfma32(kb1, qb[c], s1);
        }
        __builtin_amdgcn_s_setprio(0);

        // ---- softmax numerators in-register (bias consumed from bnx) ----
        unsigned wa[2][4], wb[2][4];
#pragma unroll
        for (int tt = 0; tt < 2; ++tt) {
#pragma unroll
            for (int u = 0; u < 4; ++u) {
                const f32x16& s = tt ? s1 : s0;
                f32x4 bvv = bnx[tt * 4 + u];
                float p0 = __builtin_amdgcn_exp2f(__builtin_fmaf(-LOG2E, bvv[0], s[4*u+0]));
                float p1 = __builtin_amdgcn_exp2f(__builtin_fmaf(-LOG2E, bvv[1], s[4*u+1]));
                float p2 = __builtin_amdgcn_exp2f(__builtin_fmaf(-LOG2E, bvv[2], s[4*u+2]));
                float p3 = __builtin_amdgcn_exp2f(__builtin_fmaf(-LOG2E, bvv[3], s[4*u+3]));
                l += (p0 + p1) + (p2 + p3);
                wa[tt][u] = pk2(p0, p1);
                wb[tt][u] = pk2(p2, p3);
            }
        }

        // prefetch next bias tile (covered by PV + next-iter QK)
        if (more) {
#pragma unroll
            for (int tt = 0; tt < 2; ++tt)
#pragma unroll
                for (int u = 0; u < 4; ++u)
                    bnx[tt * 4 + u] = *(const f32x4*)(bb + (size_t)((it + 1) * 16 + tt * 8 + 2 * u + hi) * 4096);
        }

        // ---- cross-half exchange: one swap fills word0+word2 (T12) ----
#pragma unroll
        for (int tt = 0; tt < 2; ++tt) {
            pl32swap(wa[tt][0], wa[tt][1], hi);
            pl32swap(wb[tt][0], wb[tt][1], hi);
            pl32swap(wa[tt][2], wa[tt][3], hi);
            pl32swap(wb[tt][2], wb[tt][3], hi);
        }

        // ---- PV: O^T += V^T · P^T, 4 k-chunks x 2 d-blocks ----
        __builtin_amdgcn_s_setprio(1);
#pragma unroll
        for (int tt = 0; tt < 2; ++tt)
#pragma unroll
            for (int c01 = 0; c01 < 2; ++c01) {
                int kc = tt * 2 + c01;
                i32x4 bwi = { (int)wa[tt][2*c01], (int)wb[tt][2*c01],
                              (int)wa[tt][2*c01+1], (int)wb[tt][2*c01+1] };
                bf16x8 pb = __builtin_bit_cast(bf16x8, bwi);
                int off = ((kc << 4) | hi8) ^ key8;
                bf16x8 va0 = *(const bf16x8*)(&v_lds[cur][q31][off]);
                bf16x8 va1 = *(const bf16x8*)(&v_lds[cur][32 + q31][off]);
                acc0 = mfma32(va0, pb, acc0);
                acc1 = mfma32(va1, pb, acc1);
            }
        __builtin_amdgcn_s_setprio(0);
    }

    // ---- epilogue: l split across hi-halves only; one shfl; vectorized store ----
    l += __shfl_xor(l, 32, 64);
    float inv = 1.0f / l;

    float* ob = out + ((size_t)bgh * N_ + n0 + w * 32 + q31) * D_ + hi * 4;
#pragma unroll
    for (int td = 0; td < 2; ++td) {
        const f32x16& a = td ? acc1 : acc0;
#pragma unroll
        for (int u = 0; u < 4; ++u) {
            f32x4 o = { a[4*u+0] * inv, a[4*u+1] * inv, a[4*u+2] * inv, a[4*u+3] * inv };
            *(f32x4*)(ob + td * 32 + u * 8) = o;
        }
    }
}

// ---------------------------------------------------------------------------
// Fallback (only if ws too small): naive fp32, one block per (bgh,n) row.
// ---------------------------------------------------------------------------
__global__ __launch_bounds__(256) void naive_kernel(
    const float* __restrict__ q, const float* __restrict__ k,
    const float* __restrict__ v, const float* __restrict__ bias,
    float* __restrict__ out)
{
    __shared__ float sc[N_];
    __shared__ float red[256];
    __shared__ float qrow[64];
    int n = blockIdx.x;
    int bgh = blockIdx.y;
    int bg = bgh >> 4, h = bgh & 15;
    int g = bg & (G_ - 1);
    int tid = threadIdx.x;
    const float* qr = q + ((size_t)(bg * N_ + n)) * 1024;
    if (tid < 64) qrow[tid] = qr[tid * 16 + h];
    __syncthreads();
    const float* bb = bias + (size_t)g * N_ * N_ + (size_t)n * N_;
    for (int m = tid; m < N_; m += 256) {
        const float* kr = k + ((size_t)(bg * N_ + m)) * 1024 + h;
        float dot = 0.f;
        for (int d = 0; d < 64; ++d) dot += qrow[d] * kr[d * 16];
        sc[m] = dot * 0.125f - bb[m];
    }
    __syncthreads();
    float mx = -INFINITY;
    for (int m = tid; m < N_; m += 256) mx = fmaxf(mx, sc[m]);
    red[tid] = mx; __syncthreads();
    for (int s = 128; s > 0; s >>= 1) {
        if (tid < s) red[tid] = fmaxf(red[tid], red[tid + s]);
        __syncthreads();
    }
    float M = red[0]; __syncthreads();
    float sum = 0.f;
    for (int m = tid; m < N_; m += 256) { float e = __expf(sc[m] - M); sc[m] = e; sum += e; }
    red[tid] = sum; __syncthreads();
    for (int s = 128; s > 0; s >>= 1) {
        if (tid < s) red[tid] += red[tid + s];
        __syncthreads();
    }
    float L = red[0]; __syncthreads();
    int d = tid & 63, quarter = tid >> 6;
    float acc = 0.f;
    const float* vb = v + (size_t)bg * N_ * 1024 + d * 16 + h;
    for (int m = quarter * 256; m < quarter * 256 + 256; ++m) acc += sc[m] * vb[(size_t)m * 1024];
    red[tid] = acc; __syncthreads();
    if (tid < 64) {
        float o = (red[tid] + red[tid + 64] + red[tid + 128] + red[tid + 192]) / L;
        out[((size_t)bgh * N_ + n) * 64 + d] = o;
    }
}

extern "C" void kernel_launch(void* const* d_in, const int* in_sizes, int n_in,
                              void* d_out, int out_size, void* d_ws, size_t ws_size,
                              hipStream_t stream) {
    const float* q    = (const float*)d_in[0];
    const float* k    = (const float*)d_in[1];
    const float* v    = (const float*)d_in[2];
    const float* bias = (const float*)d_in[3];
    float* out = (float*)d_out;

    const size_t elems = (size_t)BGH_ * N_ * D_;            // 8388608
    const size_t needA = 3 * elems * sizeof(bf16);          // 50.3 MB (qt,kt,vtT16)
    const size_t need  = needA + (size_t)G_ * N_ * N_ * 4;  // +16.8 MB biasX = 64 MiB

    if (ws_size >= need) {
        bf16* qt    = (bf16*)d_ws;
        bf16* ktb   = qt + elems;
        bf16* vtT16 = ktb + elems;
        float* biasX = (float*)((char*)d_ws + needA);
        transpose_fused<<<3 * 512 + 1024, 256, 0, stream>>>(q, k, v, bias, qt, ktb, vtT16, biasX);
        dim3 grid(N_ / 128, BGH_);
        flash_kernel<<<grid, 256, 0, stream>>>(qt, ktb, vtT16, biasX, out);
    } else {
        dim3 grid(N_, BGH_);
        naive_kernel<<<grid, 256, 0, stream>>>(q, k, v, bias, out);
    }
}

// Round 4
// 210.012 us; speedup vs baseline: 1.2742x; 1.0174x over previous
//
#include <hip/hip_runtime.h>
#include <hip/hip_bf16.h>
#include <math.h>

// Problem constants (GenNeuronStates): B=2,G=4,N=1024,H=16,dq=dv=64
#define B_ 2
#define G_ 4
#define N_ 1024
#define H_ 16
#define D_ 64
#define BG_ (B_*G_)
#define BGH_ (B_*G_*H_)
#define MK 64   // K/V tile rows per flash iteration
#define LOG2E 1.44269504f
#define QSCALE (0.125f * LOG2E)   // folded into Q during transpose

typedef __bf16 bf16;
typedef bf16 bf16x8 __attribute__((ext_vector_type(8)));
typedef bf16 bf16x2 __attribute__((ext_vector_type(2)));
typedef float f32x4 __attribute__((ext_vector_type(4)));
typedef float f32x16 __attribute__((ext_vector_type(16)));
typedef int i32x4 __attribute__((ext_vector_type(4)));
typedef unsigned u32x2 __attribute__((ext_vector_type(2)));

static __device__ __forceinline__ f32x16 mfma32(bf16x8 a, bf16x8 b, f32x16 c) {
    return __builtin_amdgcn_mfma_f32_32x32x16_bf16(a, b, c, 0, 0, 0);
}

// pack two f32 -> one dword of 2 bf16 (compiler emits v_cvt_pk_bf16_f32)
static __device__ __forceinline__ unsigned pk2(float a, float b) {
    bf16x2 t; t[0] = (bf16)a; t[1] = (bf16)b;
    return __builtin_bit_cast(unsigned, t);
}

// permlane32_swap: a' = {a.lo, b.lo}, b' = {a.hi, b.hi}  (halves = lanes 0-31 / 32-63)
static __device__ __forceinline__ void pl32swap(unsigned& a, unsigned& b, int hi) {
#if __has_builtin(__builtin_amdgcn_permlane32_swap)
    u32x2 r = __builtin_amdgcn_permlane32_swap(a, b, false, false);
    a = r[0]; b = r[1];
    (void)hi;
#else
    unsigned ax = (unsigned)__shfl_xor((int)a, 32, 64);
    unsigned bx = (unsigned)__shfl_xor((int)b, 32, 64);
    unsigned na = hi ? bx : a;
    unsigned nb = hi ? b : ax;
    a = na; b = nb;
#endif
}

// async global->LDS, 16B per lane; dest = wave-uniform base + lane*16 (m104)
static __device__ __forceinline__ void gll16(const void* gsrc, void* ldst, int lane) {
#if __has_builtin(__builtin_amdgcn_global_load_lds)
    (void)lane;
    __builtin_amdgcn_global_load_lds((const __attribute__((address_space(1))) void*)gsrc,
                                     (__attribute__((address_space(3))) void*)ldst, 16, 0, 0);
#else
    *(bf16x8*)((bf16*)ldst + lane * 8) = *(const bf16x8*)((const bf16*)gsrc);
#endif
}

// ---------------------------------------------------------------------------
// Fused prep pass.
//   bx < 1536 : Q/K/V transpose (V writes 16-chunked vtT16[bgh][n/16][d][16])
//   bx >= 1536: bias blocked-transpose biasX[g][m/4][q][4] (f32x4-granular)
// ---------------------------------------------------------------------------
#define HS 1160
#define NS 72

__global__ __launch_bounds__(256) void transpose_fused(
    const float* __restrict__ q, const float* __restrict__ k, const float* __restrict__ v,
    const float* __restrict__ bias,
    bf16* __restrict__ qt, bf16* __restrict__ ktb, bf16* __restrict__ vtT16,
    float* __restrict__ biasX)
{
    __shared__ __attribute__((aligned(16))) bf16 lds[16 * HS];  // 37.1 KB (reused by bias branch)
    int bx = blockIdx.x;
    int t = threadIdx.x;

    if (bx >= 3 * 512) {
        // ---- bias blocked transpose: biasX[((g*256+mb)*1024+q)*4+mo] = bias[g][q][4mb+mo]
        int idx = bx - 3 * 512;
        int gg  = idx >> 8;            // 0..3
        int tl  = idx & 255;
        int q0  = (tl >> 4) * 64;
        int m0  = (tl & 15) * 64;
        float* ldsF = (float*)lds;     // [64][68] f32, 17.4 KB

        int mi = t & 15, qr = t >> 4;
#pragma unroll
        for (int rr = 0; rr < 4; ++rr) {
            int row = qr + rr * 16;
            f32x4 val = *(const f32x4*)(bias + ((size_t)(gg * N_ + q0 + row) * N_ + m0 + 4 * mi));
            *(f32x4*)(&ldsF[row * 68 + 4 * mi]) = val;
        }
        __syncthreads();
        int qr2 = t & 63, mb0 = t >> 6;
#pragma unroll
        for (int kk = 0; kk < 4; ++kk) {
            int mbi = mb0 + kk * 4;    // 0..15
            f32x4 vv = *(const f32x4*)(&ldsF[qr2 * 68 + 4 * mbi]);
            *(f32x4*)(biasX + (((size_t)gg * 256 + m0 / 4 + mbi) * N_ + q0 + qr2) * 4) = vv;
        }
        return;
    }

    int tensor = bx >> 9;          // 512 blocks per tensor
    int rr = bx & 511;
    int bg = rr >> 6;
    int tile = rr & 63;
    int n0 = tile * 16;

    const float* src = (tensor == 0) ? q : (tensor == 1) ? k : v;
    float scale = (tensor == 0) ? QSCALE : 1.0f;
    const float* sb = src + (size_t)bg * N_ * 1024 + (size_t)n0 * 1024;

    int h0 = 4 * (t & 3);          // element j of the float4 has h = h0+j, same d
    int d  = t >> 2;
    int wbase = h0 * HS + d;
#pragma unroll 4
    for (int i = 0; i < 16; ++i) {
        float4 val = ((const float4*)(sb + (size_t)i * 1024))[t];
        bf16* p = &lds[wbase + i * NS];
        p[0]        = (bf16)(val.x * scale);
        p[HS]       = (bf16)(val.y * scale);
        p[2 * HS]   = (bf16)(val.z * scale);
        p[3 * HS]   = (bf16)(val.w * scale);
    }
    __syncthreads();

    if (tensor < 2) {
        bf16* dst = (tensor == 0) ? qt : ktb;
        int n  = (t >> 3) & 15;
        int db = t & 7;
        int hb = t >> 7;
#pragma unroll
        for (int i = 0; i < 8; ++i) {
            int h = 2 * i + hb;
            bf16x8 vv = *(const bf16x8*)(&lds[h * HS + n * NS + db * 8]);
            *(bf16x8*)(dst + (((size_t)(bg * H_ + h)) * N_ + n0 + n) * D_ + db * 8) = vv;
        }
    } else {
        // V -> vtT16[bgh][nchunk=tile][d][16]; lanes at consecutive d -> 2KB runs
        int dd = t & 63;
        int hb = t >> 6;           // 0..3
#pragma unroll
        for (int i = 0; i < 4; ++i) {
            int h = hb * 4 + i;
            bf16x8 v0, v1;
#pragma unroll
            for (int jj = 0; jj < 8; ++jj) v0[jj] = lds[h * HS + jj * NS + dd];
#pragma unroll
            for (int jj = 0; jj < 8; ++jj) v1[jj] = lds[h * HS + (8 + jj) * NS + dd];
            bf16* dst = vtT16 + (((size_t)(bg * H_ + h) * 64 + tile) * D_ + dd) * 16;
            *(bf16x8*)dst       = v0;
            *(bf16x8*)(dst + 8) = v1;
        }
    }
}

// ---------------------------------------------------------------------------
// Flash v9 = v8 + XCD-bijective block swizzle (T1, co-designed with sharing):
//   1D grid 1024; xcd = wg&7, slot = wg>>3, bgh = xcd*16 + (slot>>3),
//   qtile = slot&7. Each XCD owns 16 bgh = one (b,g): K/V read only within
//   one XCD (L2-hit after first touch), bias g-slice shared by 16 heads on
//   the same XCD. All 128 blocks of an XCD co-resident (32CU x 4) -> staging
//   loads are ~200cy L2 hits, inside the 1-iter prefetch window, so the
//   pre-barrier vmcnt(0) drain becomes ~free.
// Rest identical to v8: swapped-operand 32x32 MFMA, P in registers via
// cvt_pk+permlane32_swap, bias as coalesced f32x4 regs, gll16 staging with
// source-side swizzle + read-side XOR (rule #21), double-buffer, 1 barrier.
// ---------------------------------------------------------------------------
__global__ __launch_bounds__(256, 3) void flash_kernel(
    const bf16* __restrict__ qt, const bf16* __restrict__ kt, const bf16* __restrict__ vtT16,
    const float* __restrict__ biasX, float* __restrict__ out)
{
    __shared__ __attribute__((aligned(16))) bf16 k_lds[2][MK][D_];  // [buf][m][d] linear
    __shared__ __attribute__((aligned(16))) bf16 v_lds[2][D_][MK];  // [buf][d][m] linear

    int tid  = threadIdx.x;
    int w    = tid >> 6;
    int lane = tid & 63;
    int hi   = lane >> 5;
    int q31  = lane & 31;
    int key8 = (q31 & 7) << 3;     // elem-XOR key for frag reads (8-elem granule)
    int hi8  = hi << 3;

    // XCD-bijective swizzle: all q-tiles of a bgh + all heads of a (b,g) on ONE XCD
    int wg   = blockIdx.x;
    int xcd  = wg & 7;
    int slot = wg >> 3;            // 0..127
    int bgh  = xcd * 16 + (slot >> 3);
    int n0   = (slot & 7) * 128;
    int g    = (bgh >> 4) & (G_ - 1);   // bgh = (b*G+g)*H + h

    // Q B-frags (loop-invariant)
    const bf16* qb_base = qt + ((size_t)bgh * N_ + n0 + w * 32 + q31) * D_ + hi * 8;
    bf16x8 qb[4];
#pragma unroll
    for (int c = 0; c < 4; ++c) qb[c] = *(const bf16x8*)(qb_base + c * 16);

    f32x16 acc0 = {0,0,0,0,0,0,0,0,0,0,0,0,0,0,0,0};
    f32x16 acc1 = {0,0,0,0,0,0,0,0,0,0,0,0,0,0,0,0};
    float l = 0.f;

    // ---- staging geometry: waves 0,1 stage K rows wrow..wrow+31; waves 2,3 stage V
    int rloc = lane >> 3;              // 0..7
    int c16  = lane & 7;               // 16B chunk within 128B row
    int csw  = c16 ^ rloc;             // source chunk (row&7 == rloc for all instrs)
    bool isK = (w < 2);
    int wrow = (w & 1) * 32;
    const bf16* ksrc = kt + (size_t)bgh * N_ * D_ + (size_t)(wrow + rloc) * D_ + csw * 8;
    const bf16* vsrc = vtT16 + (((size_t)bgh * 64 + (csw >> 1)) * D_ + (wrow + rloc)) * 16 + (csw & 1) * 8;

    // ---- bias: lane's q-row column of biasX; quad (it,t,u) at mb*4096 floats
    const float* bb = biasX + (size_t)g * (256u * 1024 * 4) + (size_t)(n0 + w * 32 + q31) * 4;

    // ---- prologue: stage tile 0 + bias tile 0 ----
    if (isK) {
#pragma unroll
        for (int i = 0; i < 4; ++i) gll16(ksrc + (size_t)i * 8 * D_, &k_lds[0][wrow + i * 8][0], lane);
    } else {
#pragma unroll
        for (int i = 0; i < 4; ++i) gll16(vsrc + (size_t)i * 128, &v_lds[0][wrow + i * 8][0], lane);
    }
    f32x4 bnx[8];
#pragma unroll
    for (int tt = 0; tt < 2; ++tt)
#pragma unroll
        for (int u = 0; u < 4; ++u)
            bnx[tt * 4 + u] = *(const f32x4*)(bb + (size_t)(tt * 8 + 2 * u + hi) * 4096);

    for (int it = 0; it < N_ / MK; ++it) {
        int  cur  = it & 1;
        bool more = (it + 1 < N_ / MK);
        __syncthreads();   // drains vmcnt -> buf cur published; buf cur^1 free

        if (more) {        // async-stage next tile (fire-and-forget, drained at next barrier)
            int nxt = cur ^ 1;
            if (isK) {
                const bf16* ks = ksrc + (size_t)(it + 1) * MK * D_;
#pragma unroll
                for (int i = 0; i < 4; ++i) gll16(ks + (size_t)i * 8 * D_, &k_lds[nxt][wrow + i * 8][0], lane);
            } else {
                const bf16* vs = vsrc + (size_t)(it + 1) * 4096;
#pragma unroll
                for (int i = 0; i < 4; ++i) gll16(vs + (size_t)i * 128, &v_lds[nxt][wrow + i * 8][0], lane);
            }
        }

        // ---- QK: S^T = K·Q^T, two 32-row tiles, chained over 4 d-chunks ----
        f32x16 s0 = {0,0,0,0,0,0,0,0,0,0,0,0,0,0,0,0};
        f32x16 s1 = {0,0,0,0,0,0,0,0,0,0,0,0,0,0,0,0};
        __builtin_amdgcn_s_setprio(1);
#pragma unroll
        for (int c = 0; c < 4; ++c) {
            int off = ((c << 4) | hi8) ^ key8;
            bf16x8 kb0 = *(const bf16x8*)(&k_lds[cur][q31][off]);
            bf16x8 kb1 = *(const bf16x8*)(&k_lds[cur][32 + q31][off]);
            s0 = mfma32(kb0, qb[c], s0);
            s1 = mfma32(kb1, qb[c], s1);
        }
        __builtin_amdgcn_s_setprio(0);

        // ---- softmax numerators in-register (bias consumed from bnx) ----
        unsigned wa[2][4], wb[2][4];
#pragma unroll
        for (int tt = 0; tt < 2; ++tt) {
#pragma unroll
            for (int u = 0; u < 4; ++u) {
                const f32x16& s = tt ? s1 : s0;
                f32x4 bvv = bnx[tt * 4 + u];
                float p0 = __builtin_amdgcn_exp2f(__builtin_fmaf(-LOG2E, bvv[0], s[4*u+0]));
                float p1 = __builtin_amdgcn_exp2f(__builtin_fmaf(-LOG2E, bvv[1], s[4*u+1]));
                float p2 = __builtin_amdgcn_exp2f(__builtin_fmaf(-LOG2E, bvv[2], s[4*u+2]));
                float p3 = __builtin_amdgcn_exp2f(__builtin_fmaf(-LOG2E, bvv[3], s[4*u+3]));
                l += (p0 + p1) + (p2 + p3);
                wa[tt][u] = pk2(p0, p1);
                wb[tt][u] = pk2(p2, p3);
            }
        }

        // prefetch next bias tile (covered by PV + next-iter QK)
        if (more) {
#pragma unroll
            for (int tt = 0; tt < 2; ++tt)
#pragma unroll
                for (int u = 0; u < 4; ++u)
                    bnx[tt * 4 + u] = *(const f32x4*)(bb + (size_t)((it + 1) * 16 + tt * 8 + 2 * u + hi) * 4096);
        }

        // ---- cross-half exchange: one swap fills word0+word2 (T12) ----
#pragma unroll
        for (int tt = 0; tt < 2; ++tt) {
            pl32swap(wa[tt][0], wa[tt][1], hi);
            pl32swap(wb[tt][0], wb[tt][1], hi);
            pl32swap(wa[tt][2], wa[tt][3], hi);
            pl32swap(wb[tt][2], wb[tt][3], hi);
        }

        // ---- PV: O^T += V^T · P^T, 4 k-chunks x 2 d-blocks ----
        __builtin_amdgcn_s_setprio(1);
#pragma unroll
        for (int tt = 0; tt < 2; ++tt)
#pragma unroll
            for (int c01 = 0; c01 < 2; ++c01) {
                int kc = tt * 2 + c01;
                i32x4 bwi = { (int)wa[tt][2*c01], (int)wb[tt][2*c01],
                              (int)wa[tt][2*c01+1], (int)wb[tt][2*c01+1] };
                bf16x8 pb = __builtin_bit_cast(bf16x8, bwi);
                int off = ((kc << 4) | hi8) ^ key8;
                bf16x8 va0 = *(const bf16x8*)(&v_lds[cur][q31][off]);
                bf16x8 va1 = *(const bf16x8*)(&v_lds[cur][32 + q31][off]);
                acc0 = mfma32(va0, pb, acc0);
                acc1 = mfma32(va1, pb, acc1);
            }
        __builtin_amdgcn_s_setprio(0);
    }

    // ---- epilogue: l split across hi-halves only; one shfl; vectorized store ----
    l += __shfl_xor(l, 32, 64);
    float inv = 1.0f / l;

    float* ob = out + ((size_t)bgh * N_ + n0 + w * 32 + q31) * D_ + hi * 4;
#pragma unroll
    for (int td = 0; td < 2; ++td) {
        const f32x16& a = td ? acc1 : acc0;
#pragma unroll
        for (int u = 0; u < 4; ++u) {
            f32x4 o = { a[4*u+0] * inv, a[4*u+1] * inv, a[4*u+2] * inv, a[4*u+3] * inv };
            *(f32x4*)(ob + td * 32 + u * 8) = o;
        }
    }
}

// ---------------------------------------------------------------------------
// Fallback (only if ws too small): naive fp32, one block per (bgh,n) row.
// ---------------------------------------------------------------------------
__global__ __launch_bounds__(256) void naive_kernel(
    const float* __restrict__ q, const float* __restrict__ k,
    const float* __restrict__ v, const float* __restrict__ bias,
    float* __restrict__ out)
{
    __shared__ float sc[N_];
    __shared__ float red[256];
    __shared__ float qrow[64];
    int n = blockIdx.x;
    int bgh = blockIdx.y;
    int bg = bgh >> 4, h = bgh & 15;
    int g = bg & (G_ - 1);
    int tid = threadIdx.x;
    const float* qr = q + ((size_t)(bg * N_ + n)) * 1024;
    if (tid < 64) qrow[tid] = qr[tid * 16 + h];
    __syncthreads();
    const float* bb = bias + (size_t)g * N_ * N_ + (size_t)n * N_;
    for (int m = tid; m < N_; m += 256) {
        const float* kr = k + ((size_t)(bg * N_ + m)) * 1024 + h;
        float dot = 0.f;
        for (int d = 0; d < 64; ++d) dot += qrow[d] * kr[d * 16];
        sc[m] = dot * 0.125f - bb[m];
    }
    __syncthreads();
    float mx = -INFINITY;
    for (int m = tid; m < N_; m += 256) mx = fmaxf(mx, sc[m]);
    red[tid] = mx; __syncthreads();
    for (int s = 128; s > 0; s >>= 1) {
        if (tid < s) red[tid] = fmaxf(red[tid], red[tid + s]);
        __syncthreads();
    }
    float M = red[0]; __syncthreads();
    float sum = 0.f;
    for (int m = tid; m < N_; m += 256) { float e = __expf(sc[m] - M); sc[m] = e; sum += e; }
    red[tid] = sum; __syncthreads();
    for (int s = 128; s > 0; s >>= 1) {
        if (tid < s) red[tid] += red[tid + s];
        __syncthreads();
    }
    float L = red[0]; __syncthreads();
    int d = tid & 63, quarter = tid >> 6;
    float acc = 0.f;
    const float* vb = v + (size_t)bg * N_ * 1024 + d * 16 + h;
    for (int m = quarter * 256; m < quarter * 256 + 256; ++m) acc += sc[m] * vb[(size_t)m * 1024];
    red[tid] = acc; __syncthreads();
    if (tid < 64) {
        float o = (red[tid] + red[tid + 64] + red[tid + 128] + red[tid + 192]) / L;
        out[((size_t)bgh * N_ + n) * 64 + d] = o;
    }
}

extern "C" void kernel_launch(void* const* d_in, const int* in_sizes, int n_in,
                              void* d_out, int out_size, void* d_ws, size_t ws_size,
                              hipStream_t stream) {
    const float* q    = (const float*)d_in[0];
    const float* k    = (const float*)d_in[1];
    const float* v    = (const float*)d_in[2];
    const float* bias = (const float*)d_in[3];
    float* out = (float*)d_out;

    const size_t elems = (size_t)BGH_ * N_ * D_;            // 8388608
    const size_t needA = 3 * elems * sizeof(bf16);          // 50.3 MB (qt,kt,vtT16)
    const size_t need  = needA + (size_t)G_ * N_ * N_ * 4;  // +16.8 MB biasX = 64 MiB

    if (ws_size >= need) {
        bf16* qt    = (bf16*)d_ws;
        bf16* ktb   = qt + elems;
        bf16* vtT16 = ktb + elems;
        float* biasX = (float*)((char*)d_ws + needA);
        transpose_fused<<<3 * 512 + 1024, 256, 0, stream>>>(q, k, v, bias, qt, ktb, vtT16, biasX);
        flash_kernel<<<dim3(1024), 256, 0, stream>>>(qt, ktb, vtT16, biasX, out);
    } else {
        dim3 grid(N_, BGH_);
        naive_kernel<<<grid, 256, 0, stream>>>(q, k, v, bias, out);
    }
}